// Round 7
// baseline (520.687 us; speedup 1.0000x reference)
//
#include <hip/hip_runtime.h>
#include <hip/hip_bf16.h>

#define TCH 512
#define MTOT 16384
#define SEQ 2048
#define LN_EPS 1e-5f
#define AS1 __attribute__((address_space(1)))
#define AS3 __attribute__((address_space(3)))

typedef __attribute__((ext_vector_type(8))) __bf16 bf16x8;
typedef __attribute__((ext_vector_type(4))) float f32x4;

__device__ __forceinline__ unsigned pkbf(float a, float b) {
  union { __hip_bfloat16 h; unsigned short u; } ca, cb;
  ca.h = __float2bfloat16(a); cb.h = __float2bfloat16(b);
  return (unsigned)ca.u | ((unsigned)cb.u << 16);
}
__device__ __forceinline__ float bf_lo(unsigned u) { return __uint_as_float(u << 16); }
__device__ __forceinline__ float bf_hi(unsigned u) { return __uint_as_float(u & 0xffff0000u); }

__device__ __forceinline__ bf16x8 cvt8(float4 a, float4 b) {
  union { __hip_bfloat16 h; __bf16 v; } u;
  bf16x8 r;
  u.h = __float2bfloat16(a.x); r[0] = u.v;
  u.h = __float2bfloat16(a.y); r[1] = u.v;
  u.h = __float2bfloat16(a.z); r[2] = u.v;
  u.h = __float2bfloat16(a.w); r[3] = u.v;
  u.h = __float2bfloat16(b.x); r[4] = u.v;
  u.h = __float2bfloat16(b.y); r[5] = u.v;
  u.h = __float2bfloat16(b.z); r[6] = u.v;
  u.h = __float2bfloat16(b.w); r[7] = u.v;
  return r;
}

// log2(e)/sqrt(3): folded into wq/bq so attention uses exp2 directly
#define QSCALE 0.8329517853860118f

// ---------------- prep (also zeroes gemm tickets) ---------------------------
__global__ __launch_bounds__(256) void prep_kernel(
    const float* __restrict__ w1, const float* __restrict__ w2,
    const float* __restrict__ wo, const float* __restrict__ bo,
    const float* __restrict__ wq, const float* __restrict__ bq,
    const float* __restrict__ wk, const float* __restrict__ bk,
    const float* __restrict__ wv, const float* __restrict__ bv,
    __hip_bfloat16* __restrict__ w1b, __hip_bfloat16* __restrict__ w2b,
    float4* __restrict__ wo_eff4,
    __hip_bfloat16* __restrict__ wqkvb, float* __restrict__ qkvbias,
    unsigned* __restrict__ tickets)
{
  int i = blockIdx.x * 256 + threadIdx.x;   // grid covers 512*512 exactly
  w1b[i] = __float2bfloat16(w1[i]);
  w2b[i] = __float2bfloat16(w2[i]);
  if (i < 512) tickets[i] = 0u;
  if (i < TCH) {
    float s0 = 0.f, s1 = 0.f, s2 = 0.f;
    #pragma unroll
    for (int h = 0; h < 6; ++h) {
      s0 += wo[i*18 + h*3 + 0];
      s1 += wo[i*18 + h*3 + 1];
      s2 += wo[i*18 + h*3 + 2];
    }
    wo_eff4[i] = make_float4(s0, s1, s2, bo[i]);
  }
  if (i < 16 * TCH) {
    int row = i >> 9, k = i & 511;
    float v;
    if      (row < 3) v = wq[row * TCH + k] * QSCALE;
    else if (row < 6) v = wk[(row - 3) * TCH + k];
    else if (row < 9) v = wv[(row - 6) * TCH + k];
    else              v = 0.f;
    wqkvb[i] = __float2bfloat16(v);
  }
  if (i < 16) {
    float v;
    if      (i < 3) v = bq[i] * QSCALE;
    else if (i < 6) v = bk[i - 3];
    else if (i < 9) v = bv[i - 6];
    else            v = 0.f;
    qkvbias[i] = v;
  }
}

// ---------------- qkv via MFMA + bf16 x-copy (round-5 baseline) -------------
__global__ __launch_bounds__(256) void qkv_kernel(
    const float* __restrict__ x,
    const __hip_bfloat16* __restrict__ wqkvb, const float* __restrict__ qkvbias,
    float4* __restrict__ q4, uint4* __restrict__ kvp,
    __hip_bfloat16* __restrict__ xb)
{
  const int t = threadIdx.x, wv = t >> 6, ln = t & 63;
  const int l16 = ln & 15, quad = ln >> 4;
  const int row0 = blockIdx.x * 64 + wv * 16;

  bf16x8 bfr[16];
  #pragma unroll
  for (int ks = 0; ks < 16; ++ks)
    bfr[ks] = *reinterpret_cast<const bf16x8*>(wqkvb + l16 * TCH + ks * 32 + quad * 8);

  const float* xp = x + (size_t)(row0 + l16) * TCH + quad * 8;
  __hip_bfloat16* xo = xb + (size_t)(row0 + l16) * TCH + quad * 8;

  float4 xa0 = *(const float4*)xp,        xb0 = *(const float4*)(xp + 4);
  float4 xa1 = *(const float4*)(xp + 32), xb1 = *(const float4*)(xp + 36);
  f32x4 acc = {};
  #pragma unroll
  for (int ks = 0; ks < 16; ++ks) {
    float4 xa2 = {}, xb2 = {};
    if (ks < 14) {
      xa2 = *(const float4*)(xp + (ks + 2) * 32);
      xb2 = *(const float4*)(xp + (ks + 2) * 32 + 4);
    }
    bf16x8 af = cvt8(xa0, xb0);
    *reinterpret_cast<bf16x8*>(xo + ks * 32) = af;
    acc = __builtin_amdgcn_mfma_f32_16x16x32_bf16(af, bfr[ks], acc, 0, 0, 0);
    xa0 = xa1; xb0 = xb1; xa1 = xa2; xb1 = xb2;
  }

  __shared__ float tr[4][16][17];
  #pragma unroll
  for (int r = 0; r < 4; ++r) tr[wv][quad * 4 + r][l16] = acc[r];
  __syncthreads();

  if (ln < 32) {
    const int row  = ln & 15;
    const int grow = row0 + row;
    float c[9];
    #pragma unroll
    for (int j = 0; j < 9; ++j) c[j] = tr[wv][row][j] + qkvbias[j];
    if (ln < 16) {
      q4[grow] = make_float4(c[0], c[1], c[2], 0.f);   // pre-scaled
    } else {
      kvp[grow] = make_uint4(pkbf(c[3], c[4]), pkbf(c[5], c[6]), pkbf(c[7], c[8]), 0u);
    }
  }
}

// ---------------- attention + z@wo_eff epilogue (v5, unchanged) -------------
__global__ __launch_bounds__(1024) void attn_kernel(
    const float4* __restrict__ q4, const uint4* __restrict__ kvp,
    const float4* __restrict__ wo_eff4,
    __hip_bfloat16* __restrict__ z2b)
{
  __shared__ float4 part[16 * 64];  // 16 KB
  __shared__ float4 zbuf[64];       // 1 KB
  __shared__ float4 woL[TCH];       // 8 KB

  const int b    = blockIdx.x >> 5;
  const int qc   = blockIdx.x & 31;
  const int base = b * SEQ;
  const int tid  = threadIdx.x;
  for (int i = tid; i < TCH; i += 1024) woL[i] = wo_eff4[i];

  const int wave = tid >> 6;
  const int lane = tid & 63;
  const float4 q = q4[base + qc * 64 + lane];   // pre-scaled by log2e/sqrt(3)

  const int wu = __builtin_amdgcn_readfirstlane(wave);
  const uint4* kvw = kvp + base + wu * 128;     // wave-uniform -> s_load

  float l[4] = {}, a0[4] = {}, a1[4] = {}, a2[4] = {};
  #pragma unroll 4
  for (int i = 0; i < 32; ++i) {
    #pragma unroll
    for (int s = 0; s < 4; ++s) {               // 4 independent chains
      uint4 rec = kvw[s * 32 + i];
      float sc = bf_lo(rec.x) * q.x + bf_hi(rec.x) * q.y + bf_lo(rec.y) * q.z;
      float p = __builtin_amdgcn_exp2f(sc);
      l[s]  += p;
      a0[s] += p * bf_hi(rec.y);
      a1[s] += p * bf_lo(rec.z);
      a2[s] += p * bf_hi(rec.z);
    }
  }
  part[wave * 64 + lane] = make_float4(l[0]+l[1]+l[2]+l[3],
                                       a0[0]+a0[1]+a0[2]+a0[3],
                                       a1[0]+a1[1]+a1[2]+a1[3],
                                       a2[0]+a2[1]+a2[2]+a2[3]);
  __syncthreads();

  if (tid < 64) {
    float L = 0.f, A0 = 0.f, A1 = 0.f, A2 = 0.f;
    #pragma unroll
    for (int w = 0; w < 16; ++w) {
      float4 p = part[w * 64 + tid];
      L += p.x; A0 += p.y; A1 += p.z; A2 += p.w;
    }
    const float inv = 1.f / L;
    zbuf[tid] = make_float4(A0 * inv, A1 * inv, A2 * inv, 0.f);
  }
  __syncthreads();

  #pragma unroll
  for (int qi = 0; qi < 4; ++qi) {
    const int qloc = wave * 4 + qi;
    const float4 z = zbuf[qloc];
    unsigned* outr = (unsigned*)(z2b + (size_t)(base + qc * 64 + qloc) * TCH);
    #pragma unroll
    for (int it = 0; it < 4; ++it) {
      const int c = it * 128 + lane * 2;
      const float4 w0 = woL[c], w1 = woL[c + 1];
      outr[c >> 1] = pkbf(z.x*w0.x + z.y*w0.y + z.z*w0.z + w0.w,
                          z.x*w1.x + z.y*w1.y + z.z*w1.z + w1.w);
    }
  }
}

// ---------------- GEMM v5: 64x128 tiles, 4 blocks/CU, ticket-fused LN -------
// 1024 blocks x 256 thr. rg = bx & 255 (64-row group), cg = bx >> 8 (128-col
// group). m97-style double-buffered global_load_lds staging (24 KB LDS).
// Wave w: rows [(w>>1)*32,+32), cols [(w&1)*64,+64). After the epilogue each
// block atomicIncs tickets[rg]; the 4th block LNs the 64 rows (L2-hot).
template<typename LN_T>
__global__ __launch_bounds__(256, 4) void gemm_ln_kernel(
    const __hip_bfloat16* __restrict__ A,   // [16384, 512]
    const __hip_bfloat16* __restrict__ W,   // [512, 512], row = out col
    const float* __restrict__ bias,
    const __hip_bfloat16* __restrict__ res, // [16384, 512]
    __hip_bfloat16* __restrict__ Cout,      // res + A@W^T + bias
    float2* __restrict__ partial,           // [8][16384] (sum, sumsq)
    unsigned* __restrict__ tickets,         // [256], zeroed by prep
    const float* __restrict__ gamma, const float* __restrict__ beta,
    LN_T* __restrict__ LNout)
{
  __shared__ __align__(16) __hip_bfloat16 At[2][4][64][8];   // 8 KB
  __shared__ __align__(16) __hip_bfloat16 Wt[2][4][128][8];  // 16 KB
  __shared__ unsigned tkt;

  const int bx = blockIdx.x;
  const int rg = bx & 255, cg = bx >> 8;
  const int row0 = rg * 64, col0 = cg * 128;
  const int t = threadIdx.x, w = t >> 6, ln = t & 63;
  const int l16 = ln & 15, quad = ln >> 4;
  const int wr = w >> 1, wc = w & 1;

  auto stage = [&](int ks, int b) {
    // A-tile: 64 rows x 32 K -> 256 16B segs, 1/thread (q = wave id)
    __builtin_amdgcn_global_load_lds(
        (const AS1 void*)(A + (size_t)(row0 + ln) * TCH + ks * 32 + w * 8),
        (AS3 void*)&At[b][w][ln][0], 16, 0, 0);
    // W-tile: 128 rows x 32 K -> 512 segs, 2/thread
    #pragma unroll
    for (int j = 0; j < 2; ++j) {
      const int q = ((t >> 7) << 1) | j;      // wave-uniform
      const int row = t & 127;
      __builtin_amdgcn_global_load_lds(
          (const AS1 void*)(W + (size_t)(col0 + row) * TCH + ks * 32 + q * 8),
          (AS3 void*)&Wt[b][q][row][0], 16, 0, 0);
    }
  };

  f32x4 acc[2][4] = {};
  stage(0, 0);
  for (int ks = 0; ks < 16; ++ks) {
    const int cur = ks & 1;
    __syncthreads();
    if (ks < 15) stage(ks + 1, cur ^ 1);
    bf16x8 af[2], bf[4];
    #pragma unroll
    for (int mt = 0; mt < 2; ++mt)
      af[mt] = *reinterpret_cast<const bf16x8*>(&At[cur][quad][wr * 32 + mt * 16 + l16][0]);
    #pragma unroll
    for (int nt = 0; nt < 4; ++nt)
      bf[nt] = *reinterpret_cast<const bf16x8*>(&Wt[cur][quad][wc * 64 + nt * 16 + l16][0]);
    #pragma unroll
    for (int mt = 0; mt < 2; ++mt)
      #pragma unroll
      for (int nt = 0; nt < 4; ++nt)
        acc[mt][nt] = __builtin_amdgcn_mfma_f32_16x16x32_bf16(af[mt], bf[nt], acc[mt][nt], 0, 0, 0);
  }

  // epilogue: bias + residual + store + per-row (sum,sumsq) over our 64 cols
  #pragma unroll
  for (int mt = 0; mt < 2; ++mt) {
    #pragma unroll
    for (int r = 0; r < 4; ++r) {
      const int grow = row0 + wr * 32 + mt * 16 + quad * 4 + r;
      float s = 0.f, sq = 0.f;
      #pragma unroll
      for (int nt = 0; nt < 4; ++nt) {
        const int col = col0 + wc * 64 + nt * 16 + l16;
        float v = acc[mt][nt][r] + bias[col]
                + __bfloat162float(res[(size_t)grow * TCH + col]);
        Cout[(size_t)grow * TCH + col] = __float2bfloat16(v);
        s += v; sq += v * v;
      }
      #pragma unroll
      for (int off = 1; off < 16; off <<= 1) {
        s  += __shfl_xor(s,  off, 64);
        sq += __shfl_xor(sq, off, 64);
      }
      if (l16 == 0)
        partial[(size_t)(cg * 2 + wc) * MTOT + grow] = make_float2(s, sq);
    }
  }

  // ticket: last of the 4 col-blocks for this row-group does the LayerNorm
  __threadfence();
  __syncthreads();
  if (t == 0) tkt = atomicAdd(&tickets[rg], 1u);
  __syncthreads();
  if (tkt != 3u) return;
  __threadfence();

  const float4 g0 = *(const float4*)(gamma + ln * 8);
  const float4 g1 = *(const float4*)(gamma + ln * 8 + 4);
  const float4 b0 = *(const float4*)(beta + ln * 8);
  const float4 b1 = *(const float4*)(beta + ln * 8 + 4);
  const float gg[8] = {g0.x,g0.y,g0.z,g0.w,g1.x,g1.y,g1.z,g1.w};
  const float bb[8] = {b0.x,b0.y,b0.z,b0.w,b1.x,b1.y,b1.z,b1.w};

  for (int i = 0; i < 16; ++i) {
    const int row = row0 + w * 16 + i;
    float S = 0.f, Q = 0.f;
    #pragma unroll
    for (int j = 0; j < 8; ++j) {
      float2 p = partial[(size_t)j * MTOT + row];
      S += p.x; Q += p.y;
    }
    const float mu  = S * (1.f / TCH);
    const float var = Q * (1.f / TCH) - mu * mu;
    const float rs  = rsqrtf(var + LN_EPS);

    bf16x8 vr = *reinterpret_cast<const bf16x8*>(Cout + (size_t)row * TCH + ln * 8);
    float o[8];
    #pragma unroll
    for (int j = 0; j < 8; ++j) {
      union { __bf16 v; __hip_bfloat16 h; } u; u.v = vr[j];
      o[j] = (__bfloat162float(u.h) - mu) * rs * gg[j] + bb[j];
    }
    if constexpr (sizeof(LN_T) == 2) {
      unsigned ov[4];
      #pragma unroll
      for (int j = 0; j < 4; ++j) ov[j] = pkbf(o[2*j], o[2*j+1]);
      *(uint4*)((__hip_bfloat16*)LNout + (size_t)row * TCH + ln * 8) =
          make_uint4(ov[0], ov[1], ov[2], ov[3]);
    } else {
      float* op = (float*)LNout + (size_t)row * TCH + ln * 8;
      *(float4*)op       = make_float4(o[0], o[1], o[2], o[3]);
      *(float4*)(op + 4) = make_float4(o[4], o[5], o[6], o[7]);
    }
  }
}

// ---------------- host ------------------------------------------------------
extern "C" void kernel_launch(void* const* d_in, const int* in_sizes, int n_in,
                              void* d_out, int out_size, void* d_ws, size_t ws_size,
                              hipStream_t stream) {
  (void)in_sizes; (void)n_in; (void)out_size; (void)ws_size;
  const float* x     = (const float*)d_in[0];
  const float* wq    = (const float*)d_in[1];
  const float* bq    = (const float*)d_in[2];
  const float* wk    = (const float*)d_in[3];
  const float* bk    = (const float*)d_in[4];
  const float* wv    = (const float*)d_in[5];
  const float* bv    = (const float*)d_in[6];
  const float* wo    = (const float*)d_in[7];
  const float* bo    = (const float*)d_in[8];
  const float* w1    = (const float*)d_in[9];
  const float* b1    = (const float*)d_in[10];
  const float* w2    = (const float*)d_in[11];
  const float* b2    = (const float*)d_in[12];
  const float* gamma = (const float*)d_in[13];
  const float* beta  = (const float*)d_in[14];
  float* out = (float*)d_out;

  char* ws = (char*)d_ws;
  size_t off = 0;
  float4* q4      = (float4*)(ws + off); off += (size_t)MTOT * 16;
  uint4*  kvp     = (uint4*)(ws + off);  off += (size_t)MTOT * 16;
  float4* wo_eff4 = (float4*)(ws + off); off += (size_t)TCH * 16;
  __hip_bfloat16* w1b   = (__hip_bfloat16*)(ws + off); off += (size_t)TCH * TCH * 2;
  __hip_bfloat16* w2b   = (__hip_bfloat16*)(ws + off); off += (size_t)TCH * TCH * 2;
  __hip_bfloat16* wqkvb = (__hip_bfloat16*)(ws + off); off += (size_t)16 * TCH * 2;
  float*          qkvbias = (float*)(ws + off);        off += 64;
  unsigned*       tickets = (unsigned*)(ws + off);     off += 512 * 4;
  __hip_bfloat16* xbb = (__hip_bfloat16*)(ws + off); off += (size_t)MTOT * TCH * 2;  // 16 MB
  __hip_bfloat16* z2b = (__hip_bfloat16*)(ws + off); off += (size_t)MTOT * TCH * 2;  // 16 MB
  __hip_bfloat16* r0b = (__hip_bfloat16*)(ws + off); off += (size_t)MTOT * TCH * 2;  // 16 MB
  __hip_bfloat16* r1b = (__hip_bfloat16*)(ws + off); off += (size_t)MTOT * TCH * 2;  // 16 MB
  __hip_bfloat16* rrb = (__hip_bfloat16*)(ws + off); off += (size_t)MTOT * TCH * 2;  // 16 MB
  float2* part1 = (float2*)(ws + off); off += (size_t)8 * MTOT * 8;                  // 1 MB
  float2* part2 = (float2*)(ws + off); off += (size_t)8 * MTOT * 8;                  // 1 MB

  prep_kernel<<<(TCH*TCH)/256, 256, 0, stream>>>(
      w1, w2, wo, bo, wq, bq, wk, bk, wv, bv, w1b, w2b, wo_eff4, wqkvb, qkvbias,
      tickets);
  qkv_kernel<<<MTOT/64, 256, 0, stream>>>(x, wqkvb, qkvbias, q4, kvp, xbb);
  attn_kernel<<<MTOT/64, 1024, 0, stream>>>(q4, kvp, wo_eff4, z2b);
  // r0 = x + z2 @ w1^T + b1 ; r1 = LN(r0)  (fused via tickets[0:256])
  gemm_ln_kernel<__hip_bfloat16><<<1024, 256, 0, stream>>>(
      z2b, w1b, b1, xbb, r0b, part1, tickets, gamma, beta, r1b);
  // rr = r0 + r1 @ w2^T + b2 ; out = LN(rr) (tickets[256:512])
  gemm_ln_kernel<float><<<1024, 256, 0, stream>>>(
      r1b, w2b, b2, r0b, rrb, part2, tickets + 256, gamma, beta, out);
}

// Round 8
// 223.951 us; speedup vs baseline: 2.3250x; 2.3250x over previous
//
#include <hip/hip_runtime.h>
#include <hip/hip_bf16.h>

#define TCH 512
#define MTOT 16384
#define SEQ 2048
#define LN_EPS 1e-5f
#define AS1 __attribute__((address_space(1)))
#define AS3 __attribute__((address_space(3)))

typedef __attribute__((ext_vector_type(8))) __bf16 bf16x8;
typedef __attribute__((ext_vector_type(4))) float f32x4;

__device__ __forceinline__ unsigned pkbf(float a, float b) {
  union { __hip_bfloat16 h; unsigned short u; } ca, cb;
  ca.h = __float2bfloat16(a); cb.h = __float2bfloat16(b);
  return (unsigned)ca.u | ((unsigned)cb.u << 16);
}
__device__ __forceinline__ float bf_lo(unsigned u) { return __uint_as_float(u << 16); }
__device__ __forceinline__ float bf_hi(unsigned u) { return __uint_as_float(u & 0xffff0000u); }

__device__ __forceinline__ bf16x8 cvt8(float4 a, float4 b) {
  union { __hip_bfloat16 h; __bf16 v; } u;
  bf16x8 r;
  u.h = __float2bfloat16(a.x); r[0] = u.v;
  u.h = __float2bfloat16(a.y); r[1] = u.v;
  u.h = __float2bfloat16(a.z); r[2] = u.v;
  u.h = __float2bfloat16(a.w); r[3] = u.v;
  u.h = __float2bfloat16(b.x); r[4] = u.v;
  u.h = __float2bfloat16(b.y); r[5] = u.v;
  u.h = __float2bfloat16(b.z); r[6] = u.v;
  u.h = __float2bfloat16(b.w); r[7] = u.v;
  return r;
}

// log2(e)/sqrt(3): folded into wq/bq so attention uses exp2 directly
#define QSCALE 0.8329517853860118f

// ---------------- prep ------------------------------------------------------
__global__ __launch_bounds__(256) void prep_kernel(
    const float* __restrict__ w1, const float* __restrict__ w2,
    const float* __restrict__ wo, const float* __restrict__ bo,
    const float* __restrict__ wq, const float* __restrict__ bq,
    const float* __restrict__ wk, const float* __restrict__ bk,
    const float* __restrict__ wv, const float* __restrict__ bv,
    __hip_bfloat16* __restrict__ w1b, __hip_bfloat16* __restrict__ w2b,
    float4* __restrict__ wo_eff4,
    __hip_bfloat16* __restrict__ wqkvb, float* __restrict__ qkvbias)
{
  int i = blockIdx.x * 256 + threadIdx.x;   // grid covers 512*512 exactly
  w1b[i] = __float2bfloat16(w1[i]);
  w2b[i] = __float2bfloat16(w2[i]);
  if (i < TCH) {
    float s0 = 0.f, s1 = 0.f, s2 = 0.f;
    #pragma unroll
    for (int h = 0; h < 6; ++h) {
      s0 += wo[i*18 + h*3 + 0];
      s1 += wo[i*18 + h*3 + 1];
      s2 += wo[i*18 + h*3 + 2];
    }
    wo_eff4[i] = make_float4(s0, s1, s2, bo[i]);
  }
  if (i < 16 * TCH) {
    int row = i >> 9, k = i & 511;
    float v;
    if      (row < 3) v = wq[row * TCH + k] * QSCALE;
    else if (row < 6) v = wk[(row - 3) * TCH + k];
    else if (row < 9) v = wv[(row - 6) * TCH + k];
    else              v = 0.f;
    wqkvb[i] = __float2bfloat16(v);
  }
  if (i < 16) {
    float v;
    if      (i < 3) v = bq[i] * QSCALE;
    else if (i < 6) v = bk[i - 3];
    else if (i < 9) v = bv[i - 6];
    else            v = 0.f;
    qkvbias[i] = v;
  }
}

// ---------------- qkv via MFMA + bf16 x-copy (round-5 baseline) -------------
__global__ __launch_bounds__(256) void qkv_kernel(
    const float* __restrict__ x,
    const __hip_bfloat16* __restrict__ wqkvb, const float* __restrict__ qkvbias,
    float4* __restrict__ q4, uint4* __restrict__ kvp,
    __hip_bfloat16* __restrict__ xb)
{
  const int t = threadIdx.x, wv = t >> 6, ln = t & 63;
  const int l16 = ln & 15, quad = ln >> 4;
  const int row0 = blockIdx.x * 64 + wv * 16;

  bf16x8 bfr[16];
  #pragma unroll
  for (int ks = 0; ks < 16; ++ks)
    bfr[ks] = *reinterpret_cast<const bf16x8*>(wqkvb + l16 * TCH + ks * 32 + quad * 8);

  const float* xp = x + (size_t)(row0 + l16) * TCH + quad * 8;
  __hip_bfloat16* xo = xb + (size_t)(row0 + l16) * TCH + quad * 8;

  float4 xa0 = *(const float4*)xp,        xb0 = *(const float4*)(xp + 4);
  float4 xa1 = *(const float4*)(xp + 32), xb1 = *(const float4*)(xp + 36);
  f32x4 acc = {};
  #pragma unroll
  for (int ks = 0; ks < 16; ++ks) {
    float4 xa2 = {}, xb2 = {};
    if (ks < 14) {
      xa2 = *(const float4*)(xp + (ks + 2) * 32);
      xb2 = *(const float4*)(xp + (ks + 2) * 32 + 4);
    }
    bf16x8 af = cvt8(xa0, xb0);
    *reinterpret_cast<bf16x8*>(xo + ks * 32) = af;
    acc = __builtin_amdgcn_mfma_f32_16x16x32_bf16(af, bfr[ks], acc, 0, 0, 0);
    xa0 = xa1; xb0 = xb1; xa1 = xa2; xb1 = xb2;
  }

  __shared__ float tr[4][16][17];
  #pragma unroll
  for (int r = 0; r < 4; ++r) tr[wv][quad * 4 + r][l16] = acc[r];
  __syncthreads();

  if (ln < 32) {
    const int row  = ln & 15;
    const int grow = row0 + row;
    float c[9];
    #pragma unroll
    for (int j = 0; j < 9; ++j) c[j] = tr[wv][row][j] + qkvbias[j];
    if (ln < 16) {
      q4[grow] = make_float4(c[0], c[1], c[2], 0.f);   // pre-scaled
    } else {
      kvp[grow] = make_uint4(pkbf(c[3], c[4]), pkbf(c[5], c[6]), pkbf(c[7], c[8]), 0u);
    }
  }
}

// ---------------- attention + z@wo_eff epilogue (v5, unchanged) -------------
__global__ __launch_bounds__(1024) void attn_kernel(
    const float4* __restrict__ q4, const uint4* __restrict__ kvp,
    const float4* __restrict__ wo_eff4,
    __hip_bfloat16* __restrict__ z2b)
{
  __shared__ float4 part[16 * 64];  // 16 KB
  __shared__ float4 zbuf[64];       // 1 KB
  __shared__ float4 woL[TCH];       // 8 KB

  const int b    = blockIdx.x >> 5;
  const int qc   = blockIdx.x & 31;
  const int base = b * SEQ;
  const int tid  = threadIdx.x;
  for (int i = tid; i < TCH; i += 1024) woL[i] = wo_eff4[i];

  const int wave = tid >> 6;
  const int lane = tid & 63;
  const float4 q = q4[base + qc * 64 + lane];   // pre-scaled by log2e/sqrt(3)

  const int wu = __builtin_amdgcn_readfirstlane(wave);
  const uint4* kvw = kvp + base + wu * 128;     // wave-uniform -> s_load

  float l[4] = {}, a0[4] = {}, a1[4] = {}, a2[4] = {};
  #pragma unroll 4
  for (int i = 0; i < 32; ++i) {
    #pragma unroll
    for (int s = 0; s < 4; ++s) {               // 4 independent chains
      uint4 rec = kvw[s * 32 + i];
      float sc = bf_lo(rec.x) * q.x + bf_hi(rec.x) * q.y + bf_lo(rec.y) * q.z;
      float p = __builtin_amdgcn_exp2f(sc);
      l[s]  += p;
      a0[s] += p * bf_hi(rec.y);
      a1[s] += p * bf_lo(rec.z);
      a2[s] += p * bf_hi(rec.z);
    }
  }
  part[wave * 64 + lane] = make_float4(l[0]+l[1]+l[2]+l[3],
                                       a0[0]+a0[1]+a0[2]+a0[3],
                                       a1[0]+a1[1]+a1[2]+a1[3],
                                       a2[0]+a2[1]+a2[2]+a2[3]);
  __syncthreads();

  if (tid < 64) {
    float L = 0.f, A0 = 0.f, A1 = 0.f, A2 = 0.f;
    #pragma unroll
    for (int w = 0; w < 16; ++w) {
      float4 p = part[w * 64 + tid];
      L += p.x; A0 += p.y; A1 += p.z; A2 += p.w;
    }
    const float inv = 1.f / L;
    zbuf[tid] = make_float4(A0 * inv, A1 * inv, A2 * inv, 0.f);
  }
  __syncthreads();

  #pragma unroll
  for (int qi = 0; qi < 4; ++qi) {
    const int qloc = wave * 4 + qi;
    const float4 z = zbuf[qloc];
    unsigned* outr = (unsigned*)(z2b + (size_t)(base + qc * 64 + qloc) * TCH);
    #pragma unroll
    for (int it = 0; it < 4; ++it) {
      const int c = it * 128 + lane * 2;
      const float4 w0 = woL[c], w1 = woL[c + 1];
      outr[c >> 1] = pkbf(z.x*w0.x + z.y*w0.y + z.z*w0.z + w0.w,
                          z.x*w1.x + z.y*w1.y + z.z*w1.z + w1.w);
    }
  }
}

// ---------------- GEMM v6: high-occupancy, tiny LDS -------------------------
// 1024 blocks x 256 thr (4 waves). bx = cg*128 + rg: rg in [0,128) (128-row
// group), cg in [0,8) (64-col group). bx%8 == rg%8 -> all col-groups of a
// row-group share an XCD (A slice 2 MB, L2-resident). Wave w: rows
// [rg*128 + w*32, +32) x all 64 cols. W k-slice (64x32, 4 KB) double-buffered
// in LDS (8 KB total -> LDS never caps occupancy); A depth-2 register
// prefetch. Small per-wave state (~90 VGPR) -> ~5 blocks/CU, 20 waves/CU.
__global__ __launch_bounds__(256) void gemm_kernel(
    const __hip_bfloat16* __restrict__ A,   // [16384, 512]
    const __hip_bfloat16* __restrict__ W,   // [512, 512], row = out col
    const float* __restrict__ bias,
    const __hip_bfloat16* __restrict__ res, // [16384, 512]
    __hip_bfloat16* __restrict__ Cout,      // res + A@W^T + bias
    float2* __restrict__ partial)           // [8][16384] (sum, sumsq)
{
  __shared__ __align__(16) __hip_bfloat16 Wt[2][4][64][8];   // 8 KB

  const int bx = blockIdx.x;
  const int rg = bx & 127, cg = bx >> 7;
  const int row0 = rg * 128, col0 = cg * 64;
  const int t = threadIdx.x, w = t >> 6, ln = t & 63;
  const int l16 = ln & 15, quad = ln >> 4;

  // stage: one 16B global_load_lds per thread per k-step.
  // thread t -> col = ln, quad-slot = w (wave-uniform dest ✓)
  auto stage = [&](int ks, int b) {
    __builtin_amdgcn_global_load_lds(
        (const AS1 void*)(W + (size_t)(col0 + ln) * TCH + ks * 32 + w * 8),
        (AS3 void*)&Wt[b][w][ln][0], 16, 0, 0);
  };

  const __hip_bfloat16* Ab = A + (size_t)(row0 + w * 32 + l16) * TCH + quad * 8;

  f32x4 acc[2][4] = {};
  bf16x8 af[2], afn[2];
  af[0] = *reinterpret_cast<const bf16x8*>(Ab);
  af[1] = *reinterpret_cast<const bf16x8*>(Ab + (size_t)16 * TCH);
  stage(0, 0);

  for (int ks = 0; ks < 16; ++ks) {
    const int cur = ks & 1;
    __syncthreads();                       // Wt[cur] ready (drains vmcnt)
    if (ks < 15) {
      stage(ks + 1, cur ^ 1);              // async W for next step
      afn[0] = *reinterpret_cast<const bf16x8*>(Ab + (ks + 1) * 32);
      afn[1] = *reinterpret_cast<const bf16x8*>(Ab + (size_t)16 * TCH + (ks + 1) * 32);
    }
    bf16x8 bf[4];
    #pragma unroll
    for (int nt = 0; nt < 4; ++nt)
      bf[nt] = *reinterpret_cast<const bf16x8*>(&Wt[cur][quad][nt * 16 + l16][0]);
    #pragma unroll
    for (int mt = 0; mt < 2; ++mt)
      #pragma unroll
      for (int nt = 0; nt < 4; ++nt)
        acc[mt][nt] = __builtin_amdgcn_mfma_f32_16x16x32_bf16(af[mt], bf[nt], acc[mt][nt], 0, 0, 0);
    af[0] = afn[0]; af[1] = afn[1];
  }

  // epilogue: bias + residual + store + per-row (sum,sumsq) over our 64 cols
  #pragma unroll
  for (int mt = 0; mt < 2; ++mt) {
    #pragma unroll
    for (int r = 0; r < 4; ++r) {
      const int grow = row0 + w * 32 + mt * 16 + quad * 4 + r;
      float s = 0.f, sq = 0.f;
      #pragma unroll
      for (int nt = 0; nt < 4; ++nt) {
        const int col = col0 + nt * 16 + l16;
        float v = acc[mt][nt][r] + bias[col]
                + __bfloat162float(res[(size_t)grow * TCH + col]);
        Cout[(size_t)grow * TCH + col] = __float2bfloat16(v);
        s += v; sq += v * v;
      }
      #pragma unroll
      for (int off = 1; off < 16; off <<= 1) {
        s  += __shfl_xor(s,  off, 64);
        sq += __shfl_xor(sq, off, 64);
      }
      if (l16 == 0) partial[(size_t)cg * MTOT + grow] = make_float2(s, sq);
    }
  }
}

// ---------------- LayerNorm from partials (8 col-groups) --------------------
template<typename OUT_T>
__global__ __launch_bounds__(256) void ln_kernel(
    const __hip_bfloat16* __restrict__ Cin, const float2* __restrict__ partial,
    const float* __restrict__ gamma, const float* __restrict__ beta,
    OUT_T* __restrict__ out)
{
  const int t = threadIdx.x, wv = t >> 6, ln = t & 63;
  const int row = blockIdx.x * 4 + wv;

  float S = 0.f, Q = 0.f;
  #pragma unroll
  for (int j = 0; j < 8; ++j) {
    float2 p = partial[(size_t)j * MTOT + row];
    S += p.x; Q += p.y;
  }
  const float mu  = S * (1.f / TCH);
  const float var = Q * (1.f / TCH) - mu * mu;
  const float rs  = rsqrtf(var + LN_EPS);

  const int c0 = ln * 8;
  bf16x8 vr = *reinterpret_cast<const bf16x8*>(Cin + (size_t)row * TCH + c0);
  float4 g0 = *(const float4*)(gamma + c0), g1 = *(const float4*)(gamma + c0 + 4);
  float4 b0 = *(const float4*)(beta  + c0), b1 = *(const float4*)(beta  + c0 + 4);

  float o[8];
  const float gg[8] = {g0.x,g0.y,g0.z,g0.w,g1.x,g1.y,g1.z,g1.w};
  const float bb[8] = {b0.x,b0.y,b0.z,b0.w,b1.x,b1.y,b1.z,b1.w};
  #pragma unroll
  for (int j = 0; j < 8; ++j) {
    union { __bf16 v; __hip_bfloat16 h; } u; u.v = vr[j];
    o[j] = (__bfloat162float(u.h) - mu) * rs * gg[j] + bb[j];
  }

  if constexpr (sizeof(OUT_T) == 2) {
    unsigned ov[4];
    #pragma unroll
    for (int j = 0; j < 4; ++j) ov[j] = pkbf(o[2*j], o[2*j+1]);
    *(uint4*)((__hip_bfloat16*)out + (size_t)row * TCH + c0) =
        make_uint4(ov[0], ov[1], ov[2], ov[3]);
  } else {
    float* op = (float*)out + (size_t)row * TCH + c0;
    *(float4*)op       = make_float4(o[0], o[1], o[2], o[3]);
    *(float4*)(op + 4) = make_float4(o[4], o[5], o[6], o[7]);
  }
}

// ---------------- host ------------------------------------------------------
extern "C" void kernel_launch(void* const* d_in, const int* in_sizes, int n_in,
                              void* d_out, int out_size, void* d_ws, size_t ws_size,
                              hipStream_t stream) {
  (void)in_sizes; (void)n_in; (void)out_size; (void)ws_size;
  const float* x     = (const float*)d_in[0];
  const float* wq    = (const float*)d_in[1];
  const float* bq    = (const float*)d_in[2];
  const float* wk    = (const float*)d_in[3];
  const float* bk    = (const float*)d_in[4];
  const float* wv    = (const float*)d_in[5];
  const float* bv    = (const float*)d_in[6];
  const float* wo    = (const float*)d_in[7];
  const float* bo    = (const float*)d_in[8];
  const float* w1    = (const float*)d_in[9];
  const float* b1    = (const float*)d_in[10];
  const float* w2    = (const float*)d_in[11];
  const float* b2    = (const float*)d_in[12];
  const float* gamma = (const float*)d_in[13];
  const float* beta  = (const float*)d_in[14];
  float* out = (float*)d_out;

  char* ws = (char*)d_ws;
  size_t off = 0;
  float4* q4      = (float4*)(ws + off); off += (size_t)MTOT * 16;
  uint4*  kvp     = (uint4*)(ws + off);  off += (size_t)MTOT * 16;
  float4* wo_eff4 = (float4*)(ws + off); off += (size_t)TCH * 16;
  __hip_bfloat16* w1b   = (__hip_bfloat16*)(ws + off); off += (size_t)TCH * TCH * 2;
  __hip_bfloat16* w2b   = (__hip_bfloat16*)(ws + off); off += (size_t)TCH * TCH * 2;
  __hip_bfloat16* wqkvb = (__hip_bfloat16*)(ws + off); off += (size_t)16 * TCH * 2;
  float*          qkvbias = (float*)(ws + off);        off += 64;
  __hip_bfloat16* xbb = (__hip_bfloat16*)(ws + off); off += (size_t)MTOT * TCH * 2;  // 16 MB
  __hip_bfloat16* z2b = (__hip_bfloat16*)(ws + off); off += (size_t)MTOT * TCH * 2;  // 16 MB
  __hip_bfloat16* r0b = (__hip_bfloat16*)(ws + off); off += (size_t)MTOT * TCH * 2;  // 16 MB
  __hip_bfloat16* r1b = (__hip_bfloat16*)(ws + off); off += (size_t)MTOT * TCH * 2;  // 16 MB
  __hip_bfloat16* rrb = (__hip_bfloat16*)(ws + off); off += (size_t)MTOT * TCH * 2;  // 16 MB
  float2* part1 = (float2*)(ws + off); off += (size_t)8 * MTOT * 8;                  // 1 MB
  float2* part2 = (float2*)(ws + off); off += (size_t)8 * MTOT * 8;                  // 1 MB

  prep_kernel<<<(TCH*TCH)/256, 256, 0, stream>>>(
      w1, w2, wo, bo, wq, bq, wk, bk, wv, bv, w1b, w2b, wo_eff4, wqkvb, qkvbias);
  qkv_kernel<<<MTOT/64, 256, 0, stream>>>(x, wqkvb, qkvbias, q4, kvp, xbb);
  attn_kernel<<<MTOT/64, 1024, 0, stream>>>(q4, kvp, wo_eff4, z2b);
  // r0 = x + z2 @ w1^T + b1
  gemm_kernel<<<1024, 256, 0, stream>>>(z2b, w1b, b1, xbb, r0b, part1);
  // r1 = LN(r0)
  ln_kernel<__hip_bfloat16><<<MTOT/4, 256, 0, stream>>>(r0b, part1, gamma, beta, r1b);
  // rr = r0 + r1 @ w2^T + b2
  gemm_kernel<<<1024, 256, 0, stream>>>(r1b, w2b, b2, r0b, rrb, part2);
  // out = LN(rr)
  ln_kernel<float><<<MTOT/4, 256, 0, stream>>>(rrb, part2, gamma, beta, out);
}